// Round 2
// baseline (666.702 us; speedup 1.0000x reference)
//
#include <hip/hip_runtime.h>
#include <hip/hip_bf16.h>
#include <stdint.h>

#define HDIM 128
#define SBITS 8
#define SBMASK 255
#define SBMAX 512  // supports N <= 131072

typedef __attribute__((ext_vector_type(8))) short short8;
typedef __attribute__((ext_vector_type(4))) float f32x4;
typedef __attribute__((ext_vector_type(2))) float f32x2;

__device__ __forceinline__ ushort f2bf(float f) {
  uint u = __float_as_uint(f);
  u = (u + 0x7fffu + ((u >> 16) & 1u)) >> 16;
  return (ushort)u;
}
__device__ __forceinline__ float bflo(uint v) { return __uint_as_float(v << 16); }
__device__ __forceinline__ float bfhi(uint v) { return __uint_as_float(v & 0xffff0000u); }

// padded degree: deg = cnt+1 padded to multiple of 4
__device__ __forceinline__ int pdeg4(int c) { return (c + 4) & ~3; }

// packed colw entry: src (17 bits) | bf15 weight << 17 (weight in (0,1])
__device__ __forceinline__ uint pack_cw(int src, float w) {
  uint w15 = (__float_as_uint(w) + 0x8000u) >> 16;
  return (uint)src | (w15 << 17);
}
__device__ __forceinline__ uint cw_src(uint u) { return u & 0x1FFFFu; }
__device__ __forceinline__ float cw_w(uint u) { return __uint_as_float((u >> 17) << 16); }

// ---------------- setup: CSR build with zero global RMW hotspots ----------------

// Edge stream -> SB sub-buckets of 256 dst nodes. Entry: d_local(8b)|src<<8.
// LDS-hist ranking; ONE allocator atomic per sub-bucket per block.
__global__ __launch_bounds__(256) void bucket_edges(const int* __restrict__ ei,
                                                    int* __restrict__ bktcur,
                                                    uint* __restrict__ bkt, int E,
                                                    int cap) {
  __shared__ int hist[SBMAX], base[SBMAX];
  const int t = threadIdx.x;
  const int c0 = blockIdx.x * 2048;
  for (int i = t; i < SBMAX; i += 256) hist[i] = 0;
  __syncthreads();
  uint pk[8];
  int sb_[8], rk[8];
#pragma unroll
  for (int j = 0; j < 8; ++j) {
    int idx = c0 + j * 256 + t;
    sb_[j] = -1;
    if (idx < E) {
      int s = ei[idx];
      int d = ei[E + idx];
      int b = d >> SBITS;
      pk[j] = (uint)(d & SBMASK) | ((uint)s << SBITS);
      sb_[j] = b;
      rk[j] = atomicAdd(&hist[b], 1);
    }
  }
  __syncthreads();
  for (int i = t; i < SBMAX; i += 256)
    base[i] = hist[i] ? atomicAdd(&bktcur[i * 16], hist[i]) : 0;
  __syncthreads();
#pragma unroll
  for (int j = 0; j < 8; ++j)
    if (sb_[j] >= 0)
      bkt[(size_t)sb_[j] * cap + base[sb_[j]] + rk[j]] = pk[j];
}

// One block owns one 256-node sub-bucket: LDS count -> dis + degs + padded total.
__global__ __launch_bounds__(256) void csr_count(const uint* __restrict__ bkt,
                                                 const int* __restrict__ bktcur,
                                                 float* __restrict__ dis,
                                                 int* __restrict__ degs,
                                                 int* __restrict__ sbtot, int cap,
                                                 int N) {
  __shared__ int cnt[256];
  __shared__ int red[256];
  const int sb = blockIdx.x, t = threadIdx.x;
  const int n0 = sb << SBITS;
  const int ecnt = bktcur[sb * 16];
  const uint* eb = bkt + (size_t)sb * cap;
  cnt[t] = 0;
  __syncthreads();
  for (int i = t; i < ecnt; i += 256)
    atomicAdd(&cnt[__builtin_nontemporal_load(eb + i) & SBMASK], 1);
  __syncthreads();
  int s = 0;
  const int n = n0 + t;
  if (n < N) {
    int c = cnt[t];
    degs[n] = c;
    dis[n] = rsqrtf((float)(c + 1));
    s = pdeg4(c);
  }
  red[t] = s;
  __syncthreads();
  for (int off = 128; off; off >>= 1) {
    if (t < off) red[t] += red[t + off];
    __syncthreads();
  }
  if (t == 0) sbtot[sb] = red[0];
}

// Exclusive scan of SB sub-bucket totals (SB <= 512); also writes rowptr[N].
__global__ __launch_bounds__(512) void scan_sb(const int* __restrict__ sbtot,
                                               int* __restrict__ sbbase,
                                               int* __restrict__ rowptr, int SB,
                                               int N) {
  __shared__ int sh[SBMAX];
  int t = threadIdx.x;
  int v = (t < SB) ? sbtot[t] : 0;
  sh[t] = v;
  __syncthreads();
  for (int off = 1; off < SBMAX; off <<= 1) {
    int add = (t >= off) ? sh[t - off] : 0;
    __syncthreads();
    sh[t] += add;
    __syncthreads();
  }
  if (t < SB) sbbase[t] = sh[t] - v;
  if (t == SBMAX - 1) rowptr[N] = sh[SBMAX - 1];
}

// One block owns one sub-bucket: load degs (no recount), LDS prefix, write
// rowptr (coalesced), place self-loop/pads/edges via LDS cursors. NO global
// atomics; one writer CU per colw range.
__global__ __launch_bounds__(256) void csr_place(const uint* __restrict__ bkt,
                                                 const int* __restrict__ bktcur,
                                                 const int* __restrict__ sbbase,
                                                 const float* __restrict__ dis,
                                                 const int* __restrict__ degs,
                                                 int* __restrict__ rowptr,
                                                 uint* __restrict__ colw, int cap,
                                                 int N) {
  __shared__ int cur[256];
  __shared__ int sh[256];
  const int sb = blockIdx.x, t = threadIdx.x;
  const int n0 = sb << SBITS;
  const int ecnt = bktcur[sb * 16];
  const uint* eb = bkt + (size_t)sb * cap;
  const int base = sbbase[sb];
  const int n = n0 + t;
  const int deg = (n < N) ? degs[n] : 0;
  const int v = (n < N) ? pdeg4(deg) : 0;
  sh[t] = v;
  __syncthreads();
  for (int off = 1; off < 256; off <<= 1) {
    int add = (t >= off) ? sh[t - off] : 0;
    __syncthreads();
    sh[t] += add;
    __syncthreads();
  }
  const int p = sh[t] - v;
  if (n < N) {
    rowptr[n] = base + p;
    cur[t] = p + 1;  // self-loop occupies slot p
    float dn = dis[n];
    colw[base + p] = pack_cw(n, dn * dn);
    for (int q = deg + 1; q < v; ++q) colw[base + p + q] = (uint)n;  // pads
  }
  __syncthreads();
  for (int i = t; i < ecnt; i += 256) {
    uint u = __builtin_nontemporal_load(eb + i);
    int dloc = (int)(u & SBMASK);
    int s2 = (int)(u >> SBITS);
    int pos = atomicAdd(&cur[dloc], 1);  // LDS cursor
    int d = n0 + dloc;
    colw[base + pos] = pack_cw(s2, dis[s2] * dis[d]);
  }
}

// Pre-swizzle Ws into MFMA B-fragment order per layer
__global__ __launch_bounds__(256) void swz_w(const float* __restrict__ Ws,
                                             ushort* __restrict__ Wsw, int total) {
  int idx = blockIdx.x * 256 + threadIdx.x;
  if (idx >= total) return;
  int l = idx >> 14, r = idx & 16383;
  int j = r & 7, lane = (r >> 3) & 63, kk = (r >> 9) & 3, c = r >> 11;
  int n = c * 16 + (lane & 15);
  int k = kk * 32 + (lane >> 4) * 8 + j;
  Wsw[idx] = f2bf(Ws[l * 16384 + k * HDIM + n]);
}

// ---------------- per-layer kernels (row-major activations) ----------------

// XW = X @ W. Persistent: W staged in LDS once; dynamic tile grab via global
// atomic counter (perfect load balance; static 2.04 tiles/block left a 27-block
// 3rd-tile tail).
template <bool F32IN>
__global__ __launch_bounds__(256) void gemm_kernel(const void* __restrict__ Xin,
                                                   const ushort* __restrict__ Wsw,
                                                   ushort* __restrict__ XW, int N,
                                                   int ntiles, int* __restrict__ ctr) {
  __shared__ ushort wlds[16384];    // 32 KB swizzled W (persistent)
  __shared__ ushort clds[64 * 136]; // C restage, padded stride
  __shared__ int tsh;
  const int t = threadIdx.x;
  {
    const int4* src = (const int4*)Wsw;
    int4* dst = (int4*)wlds;
#pragma unroll
    for (int i = 0; i < 8; ++i) dst[t + 256 * i] = src[t + 256 * i];
  }

  const int wave = t >> 6, lane = t & 63;
  const int kq = lane >> 4;  // 0..3

  for (;;) {
    if (t == 0) tsh = atomicAdd(ctr, 1);
    __syncthreads();  // tsh visible; prev tile's clds readers done; wlds staged
    const int tile = tsh;
    if (tile >= ntiles) break;

    const int row0 = tile * 64 + wave * 16 + (lane & 15);
    const bool inb = row0 < N;

    short8 afr[4];
#pragma unroll
    for (int kk = 0; kk < 4; ++kk) afr[kk] = short8{0, 0, 0, 0, 0, 0, 0, 0};
    if (inb) {
      if constexpr (F32IN) {
        const float* arow = (const float*)Xin + (size_t)row0 * HDIM;
#pragma unroll
        for (int kk = 0; kk < 4; ++kk) {
          float4 x0 = *(const float4*)(arow + kk * 32 + kq * 8);
          float4 x1 = *(const float4*)(arow + kk * 32 + kq * 8 + 4);
          short8 f;
          f[0] = (short)f2bf(x0.x); f[1] = (short)f2bf(x0.y);
          f[2] = (short)f2bf(x0.z); f[3] = (short)f2bf(x0.w);
          f[4] = (short)f2bf(x1.x); f[5] = (short)f2bf(x1.y);
          f[6] = (short)f2bf(x1.z); f[7] = (short)f2bf(x1.w);
          afr[kk] = f;
        }
      } else {
        const short8* arow = (const short8*)((const ushort*)Xin + (size_t)row0 * HDIM);
#pragma unroll
        for (int kk = 0; kk < 4; ++kk) afr[kk] = arow[kk * 4 + kq];
      }
    }

    f32x4 acc[8];
#pragma unroll
    for (int c = 0; c < 8; ++c) acc[c] = f32x4{0.f, 0.f, 0.f, 0.f};
#pragma unroll
    for (int kk = 0; kk < 4; ++kk) {
#pragma unroll
      for (int c = 0; c < 8; ++c) {
        short8 bfr = *(const short8*)(wlds + (((c * 4 + kk) * 64 + lane) << 3));
        acc[c] = __builtin_amdgcn_mfma_f32_16x16x32_bf16(afr[kk], bfr, acc[c], 0, 0, 0);
      }
    }

    __syncthreads();  // all compute done (clds free)
    const int m0 = wave * 16 + kq * 4;
#pragma unroll
    for (int c = 0; c < 8; ++c) {
      int col = c * 16 + (lane & 15);
#pragma unroll
      for (int r = 0; r < 4; ++r) clds[(m0 + r) * 136 + col] = f2bf(acc[c][r]);
    }
    __syncthreads();
    // coalesced store: 64 rows x 16 int4
#pragma unroll
    for (int i = 0; i < 4; ++i) {
      int idx = t + 256 * i;
      int row = idx >> 4, piece = idx & 15;
      int grow = tile * 64 + row;
      if (grow < N)
        ((int4*)XW)[(size_t)tile * 1024 + idx] =
            *(const int4*)(clds + row * 136 + piece * 8);
    }
  }
}

// Aggregation: one node per wave. lane = e*16+c; 16 lanes x uint4 = full 256B
// row per edge, 4 edges per gather instruction. Dynamic trip count (exactly
// ceil(pdeg/4) batches; avg 4.7 vs old fixed 6) with 3-deep software pipeline;
// weight clamping only in the 3-batch epilogue.
__global__ __launch_bounds__(256, 8) void agg_kernel(const ushort* __restrict__ XW,
                                                     const uint* __restrict__ colw,
                                                     const int* __restrict__ rowptr,
                                                     const float* __restrict__ bias,
                                                     ushort* __restrict__ Y, int N) {
  const int lane = threadIdx.x & 63;
  const int node = blockIdx.x * 4 + (threadIdx.x >> 6);
  if (node >= N) return;
  const int e = lane >> 4, c = lane & 15;
  const int beg = rowptr[node];
  const int pdeg = rowptr[node + 1] - beg;  // multiple of 4, >= 4
  const int nb = pdeg >> 2;                 // number of 4-edge batches
  const int last = pdeg - 1;

  f32x2 acc[4];
#pragma unroll
  for (int i = 0; i < 4; ++i) acc[i] = f32x2{0.f, 0.f};

  auto fma8 = [&](float w, uint4 v) {
    f32x2 wv = f32x2{w, w};
    acc[0] = __builtin_elementwise_fma(wv, f32x2{bflo(v.x), bfhi(v.x)}, acc[0]);
    acc[1] = __builtin_elementwise_fma(wv, f32x2{bflo(v.y), bfhi(v.y)}, acc[1]);
    acc[2] = __builtin_elementwise_fma(wv, f32x2{bflo(v.z), bfhi(v.z)}, acc[2]);
    acc[3] = __builtin_elementwise_fma(wv, f32x2{bflo(v.w), bfhi(v.w)}, acc[3]);
  };

  // prologue: 3 batches in flight (clamped for nb<3; duplicates zero-weighted
  // in the epilogue)
  const int o1 = 4 + e, o2 = 8 + e;
  uint cw0 = __builtin_nontemporal_load(colw + beg + e);
  uint cw1 = __builtin_nontemporal_load(colw + beg + (o1 < pdeg ? o1 : last));
  uint cw2 = __builtin_nontemporal_load(colw + beg + (o2 < pdeg ? o2 : last));
  uint4 gv0 = *(const uint4*)(XW + ((size_t)cw_src(cw0) << 7) + c * 8);
  uint4 gv1 = *(const uint4*)(XW + ((size_t)cw_src(cw1) << 7) + c * 8);
  uint4 gv2 = *(const uint4*)(XW + ((size_t)cw_src(cw2) << 7) + c * 8);

  // steady state: all offsets in range, full weights
  for (int b = 3; b < nb; ++b) {
    uint cwn = __builtin_nontemporal_load(colw + beg + 4 * b + e);
    uint4 gvn = *(const uint4*)(XW + ((size_t)cw_src(cwn) << 7) + c * 8);
    fma8(cw_w(cw0), gv0);
    cw0 = cw1; gv0 = gv1;
    cw1 = cw2; gv1 = gv2;
    cw2 = cwn; gv2 = gvn;
  }
  // epilogue: pending batches at offsets p0, p0+4, p0+8 (+e)
  const int p0 = (nb > 3 ? (nb - 3) * 4 : 0) + e;
  fma8(p0 < pdeg ? cw_w(cw0) : 0.f, gv0);
  fma8(p0 + 4 < pdeg ? cw_w(cw1) : 0.f, gv1);
  fma8(p0 + 8 < pdeg ? cw_w(cw2) : 0.f, gv2);

#pragma unroll
  for (int i = 0; i < 4; ++i) {
    acc[i].x += __shfl_xor(acc[i].x, 16, 64);
    acc[i].y += __shfl_xor(acc[i].y, 16, 64);
    acc[i].x += __shfl_xor(acc[i].x, 32, 64);
    acc[i].y += __shfl_xor(acc[i].y, 32, 64);
  }
  if (e == 0) {
    float4 b0 = *(const float4*)(bias + c * 8);
    float4 b1 = *(const float4*)(bias + c * 8 + 4);
    uint4 pk;
    pk.x = (uint)f2bf(fmaxf(acc[0].x + b0.x, 0.f)) | ((uint)f2bf(fmaxf(acc[0].y + b0.y, 0.f)) << 16);
    pk.y = (uint)f2bf(fmaxf(acc[1].x + b0.z, 0.f)) | ((uint)f2bf(fmaxf(acc[1].y + b0.w, 0.f)) << 16);
    pk.z = (uint)f2bf(fmaxf(acc[2].x + b1.x, 0.f)) | ((uint)f2bf(fmaxf(acc[2].y + b1.y, 0.f)) << 16);
    pk.w = (uint)f2bf(fmaxf(acc[3].x + b1.z, 0.f)) | ((uint)f2bf(fmaxf(acc[3].y + b1.w, 0.f)) << 16);
    *(uint4*)(Y + (size_t)node * HDIM + c * 8) = pk;
  }
}

// ---------------- pooling + head ----------------

__global__ __launch_bounds__(256) void pool_partial(const ushort* __restrict__ x,
                                                    const int* __restrict__ batch,
                                                    float* __restrict__ pooled,
                                                    int* __restrict__ gcnt, int N) {
  const int g = blockIdx.x, s = blockIdx.y;  // gridDim.y = 8 splits
  const int t = threadIdx.x;
  __shared__ int range[2];
  __shared__ float sums[256];
  if (t < 2) {
    int target = g + t;
    int lo = 0, hi = N;
    while (lo < hi) {
      int mid = (lo + hi) >> 1;
      if (batch[mid] < target) lo = mid + 1;
      else hi = mid;
    }
    range[t] = lo;
  }
  __syncthreads();
  int beg = range[0], end = range[1];
  if (s == 0 && t == 0) gcnt[g] = end - beg;
  int col = t & 127, half = t >> 7;
  float acc = 0.f;
  for (int n = beg + s * 2 + half; n < end; n += 16) {
    acc += __uint_as_float(((uint)x[(size_t)n * HDIM + col]) << 16);
  }
  sums[t] = acc;
  __syncthreads();
  if (t < 128) atomicAdd(&pooled[g * HDIM + t], sums[t] + sums[t + 128]);
}

__global__ __launch_bounds__(256) void out_final(const float* __restrict__ pooled,
                                                 const int* __restrict__ gcnt,
                                                 const float* __restrict__ W_out,
                                                 const float* __restrict__ b_out,
                                                 float* __restrict__ out, int G, int C) {
  int i = blockIdx.x * 256 + threadIdx.x;
  if (i >= G * C) return;
  int g = i / C, c = i - g * C;
  float inv = 1.f / (float)max(gcnt[g], 1);
  const float* pg = pooled + g * HDIM;
  float o = 0.f;
  for (int h = 0; h < HDIM; ++h) o += pg[h] * W_out[h * C + c];
  out[i] = b_out[c] + o * inv;
}

// ---------------- host ----------------

extern "C" void kernel_launch(void* const* d_in, const int* in_sizes, int n_in,
                              void* d_out, int out_size, void* d_ws, size_t ws_size,
                              hipStream_t stream) {
  (void)n_in;
  (void)ws_size;
  const float* x = (const float*)d_in[0];
  const int* ei = (const int*)d_in[1];
  const int* batch = (const int*)d_in[2];
  const float* Ws = (const float*)d_in[4];
  const float* bs = (const float*)d_in[5];
  const float* W_out = (const float*)d_in[6];
  const float* b_out = (const float*)d_in[7];
  float* out = (float*)d_out;

  const int N = in_sizes[0] / HDIM;
  const int E = in_sizes[1] / 2;
  const int L = in_sizes[5] / HDIM;
  const int C = in_sizes[7];
  const int G = out_size / C;
  const int SB = (N + SBMASK) >> SBITS;      // sub-buckets of 256 nodes
  const int cap = E / SB + 2048;             // per-sub-bucket capacity (~32 sigma)

  char* p = (char*)d_ws;
  auto carve = [&](size_t bytes) {
    char* r = p;
    p += (bytes + 255) & ~(size_t)255;
    return r;
  };
  int* bktcur = (int*)carve(SBMAX * 64 + 256);  // +64B line of gemm tile counters
  int* gctr = bktcur + SBMAX * 16;              // L ints (L <= 16)
  float* dis = (float*)carve((size_t)N * 4);
  int* degs = (int*)carve((size_t)N * 4);
  int* rowptr = (int*)carve((size_t)(N + 1) * 4);
  int* sbtot = (int*)carve(SBMAX * 4);
  int* sbbase = (int*)carve(SBMAX * 4);
  uint* bkt = (uint*)carve((size_t)SB * cap * 4);
  uint* colw = (uint*)carve(((size_t)E + 4 * (size_t)N + 64) * 4);
  ushort* Wsw = (ushort*)carve((size_t)L * HDIM * HDIM * 2);
  ushort* xw = (ushort*)carve((size_t)N * HDIM * 2);
  ushort* y0 = (ushort*)carve((size_t)N * HDIM * 2);
  ushort* y1 = (ushort*)carve((size_t)N * HDIM * 2);
  float* pooled = (float*)carve((size_t)G * HDIM * 4 + (size_t)G * 4);
  int* gcnt = (int*)(pooled + (size_t)G * HDIM);

  hipMemsetAsync(bktcur, 0, SBMAX * 64 + 256, stream);
  hipMemsetAsync(pooled, 0, (size_t)G * HDIM * 4 + (size_t)G * 4, stream);

  bucket_edges<<<(E + 2047) / 2048, 256, 0, stream>>>(ei, bktcur, bkt, E, cap);
  csr_count<<<SB, 256, 0, stream>>>(bkt, bktcur, dis, degs, sbtot, cap, N);
  scan_sb<<<1, SBMAX, 0, stream>>>(sbtot, sbbase, rowptr, SB, N);
  csr_place<<<SB, 256, 0, stream>>>(bkt, bktcur, sbbase, dis, degs, rowptr, colw, cap, N);
  swz_w<<<(L * HDIM * HDIM + 255) / 256, 256, 0, stream>>>(Ws, Wsw, L * HDIM * HDIM);

  const int ntiles = (N + 63) / 64;
  const int gb = 768;  // persistent: 3 blocks/CU (49.4 KB LDS)
  gemm_kernel<true><<<gb, 256, 0, stream>>>(x, Wsw, xw, N, ntiles, gctr);
  agg_kernel<<<(N + 3) / 4, 256, 0, stream>>>(xw, colw, rowptr, bs, y0, N);
  ushort* xc = y0;
  ushort* xn = y1;
  for (int l = 1; l < L; ++l) {
    gemm_kernel<false><<<gb, 256, 0, stream>>>(xc, Wsw + (size_t)l * HDIM * HDIM, xw, N,
                                               ntiles, gctr + l);
    agg_kernel<<<(N + 3) / 4, 256, 0, stream>>>(xw, colw, rowptr, bs + (size_t)l * HDIM, xn, N);
    ushort* tmp = xc;
    xc = xn;
    xn = tmp;
  }
  pool_partial<<<dim3(G, 8), 256, 0, stream>>>(xc, batch, pooled, gcnt, N);
  out_final<<<(G * C + 255) / 256, 256, 0, stream>>>(pooled, gcnt, W_out, b_out, out, G, C);
}

// Round 3
// 569.929 us; speedup vs baseline: 1.1698x; 1.1698x over previous
//
#include <hip/hip_runtime.h>
#include <hip/hip_bf16.h>
#include <stdint.h>

#define HDIM 128
#define SBITS 8
#define SBMASK 255
#define SBMAX 512  // supports N <= 131072

typedef __attribute__((ext_vector_type(8))) short short8;
typedef __attribute__((ext_vector_type(4))) float f32x4;
typedef __attribute__((ext_vector_type(2))) float f32x2;

__device__ __forceinline__ ushort f2bf(float f) {
  uint u = __float_as_uint(f);
  u = (u + 0x7fffu + ((u >> 16) & 1u)) >> 16;
  return (ushort)u;
}
__device__ __forceinline__ float bflo(uint v) { return __uint_as_float(v << 16); }
__device__ __forceinline__ float bfhi(uint v) { return __uint_as_float(v & 0xffff0000u); }

// padded degree: deg = cnt+1 padded to multiple of 4
__device__ __forceinline__ int pdeg4(int c) { return (c + 4) & ~3; }

// packed colw entry: src (17 bits) | bf15 weight << 17 (weight in (0,1])
__device__ __forceinline__ uint pack_cw(int src, float w) {
  uint w15 = (__float_as_uint(w) + 0x8000u) >> 16;
  return (uint)src | (w15 << 17);
}
__device__ __forceinline__ uint cw_src(uint u) { return u & 0x1FFFFu; }
__device__ __forceinline__ float cw_w(uint u) { return __uint_as_float((u >> 17) << 16); }

// ---------------- setup: CSR build with zero global RMW hotspots ----------------

// Edge stream -> SB sub-buckets of 256 dst nodes. Entry: d_local(8b)|src<<8.
// LDS-hist ranking; ONE allocator atomic per sub-bucket per block.
__global__ __launch_bounds__(256) void bucket_edges(const int* __restrict__ ei,
                                                    int* __restrict__ bktcur,
                                                    uint* __restrict__ bkt, int E,
                                                    int cap) {
  __shared__ int hist[SBMAX], base[SBMAX];
  const int t = threadIdx.x;
  const int c0 = blockIdx.x * 2048;
  for (int i = t; i < SBMAX; i += 256) hist[i] = 0;
  __syncthreads();
  uint pk[8];
  int sb_[8], rk[8];
#pragma unroll
  for (int j = 0; j < 8; ++j) {
    int idx = c0 + j * 256 + t;
    sb_[j] = -1;
    if (idx < E) {
      int s = ei[idx];
      int d = ei[E + idx];
      int b = d >> SBITS;
      pk[j] = (uint)(d & SBMASK) | ((uint)s << SBITS);
      sb_[j] = b;
      rk[j] = atomicAdd(&hist[b], 1);
    }
  }
  __syncthreads();
  for (int i = t; i < SBMAX; i += 256)
    base[i] = hist[i] ? atomicAdd(&bktcur[i * 16], hist[i]) : 0;
  __syncthreads();
#pragma unroll
  for (int j = 0; j < 8; ++j)
    if (sb_[j] >= 0)
      bkt[(size_t)sb_[j] * cap + base[sb_[j]] + rk[j]] = pk[j];
}

// One block owns one 256-node sub-bucket: LDS count -> dis + degs + padded total.
__global__ __launch_bounds__(256) void csr_count(const uint* __restrict__ bkt,
                                                 const int* __restrict__ bktcur,
                                                 float* __restrict__ dis,
                                                 int* __restrict__ degs,
                                                 int* __restrict__ sbtot, int cap,
                                                 int N) {
  __shared__ int cnt[256];
  __shared__ int red[256];
  const int sb = blockIdx.x, t = threadIdx.x;
  const int n0 = sb << SBITS;
  const int ecnt = bktcur[sb * 16];
  const uint* eb = bkt + (size_t)sb * cap;
  cnt[t] = 0;
  __syncthreads();
  for (int i = t; i < ecnt; i += 256)
    atomicAdd(&cnt[__builtin_nontemporal_load(eb + i) & SBMASK], 1);
  __syncthreads();
  int s = 0;
  const int n = n0 + t;
  if (n < N) {
    int c = cnt[t];
    degs[n] = c;
    dis[n] = rsqrtf((float)(c + 1));
    s = pdeg4(c);
  }
  red[t] = s;
  __syncthreads();
  for (int off = 128; off; off >>= 1) {
    if (t < off) red[t] += red[t + off];
    __syncthreads();
  }
  if (t == 0) sbtot[sb] = red[0];
}

// Exclusive scan of SB sub-bucket totals (SB <= 512); also writes rowptr[N].
__global__ __launch_bounds__(512) void scan_sb(const int* __restrict__ sbtot,
                                               int* __restrict__ sbbase,
                                               int* __restrict__ rowptr, int SB,
                                               int N) {
  __shared__ int sh[SBMAX];
  int t = threadIdx.x;
  int v = (t < SB) ? sbtot[t] : 0;
  sh[t] = v;
  __syncthreads();
  for (int off = 1; off < SBMAX; off <<= 1) {
    int add = (t >= off) ? sh[t - off] : 0;
    __syncthreads();
    sh[t] += add;
    __syncthreads();
  }
  if (t < SB) sbbase[t] = sh[t] - v;
  if (t == SBMAX - 1) rowptr[N] = sh[SBMAX - 1];
}

// One block owns one sub-bucket: load degs (no recount), LDS prefix, write
// rowptr (coalesced), place self-loop/pads/edges via LDS cursors. NO global
// atomics; one writer CU per colw range.
__global__ __launch_bounds__(256) void csr_place(const uint* __restrict__ bkt,
                                                 const int* __restrict__ bktcur,
                                                 const int* __restrict__ sbbase,
                                                 const float* __restrict__ dis,
                                                 const int* __restrict__ degs,
                                                 int* __restrict__ rowptr,
                                                 uint* __restrict__ colw, int cap,
                                                 int N) {
  __shared__ int cur[256];
  __shared__ int sh[256];
  const int sb = blockIdx.x, t = threadIdx.x;
  const int n0 = sb << SBITS;
  const int ecnt = bktcur[sb * 16];
  const uint* eb = bkt + (size_t)sb * cap;
  const int base = sbbase[sb];
  const int n = n0 + t;
  const int deg = (n < N) ? degs[n] : 0;
  const int v = (n < N) ? pdeg4(deg) : 0;
  sh[t] = v;
  __syncthreads();
  for (int off = 1; off < 256; off <<= 1) {
    int add = (t >= off) ? sh[t - off] : 0;
    __syncthreads();
    sh[t] += add;
    __syncthreads();
  }
  const int p = sh[t] - v;
  if (n < N) {
    rowptr[n] = base + p;
    cur[t] = p + 1;  // self-loop occupies slot p
    float dn = dis[n];
    colw[base + p] = pack_cw(n, dn * dn);
    for (int q = deg + 1; q < v; ++q) colw[base + p + q] = (uint)n;  // pads
  }
  __syncthreads();
  for (int i = t; i < ecnt; i += 256) {
    uint u = __builtin_nontemporal_load(eb + i);
    int dloc = (int)(u & SBMASK);
    int s2 = (int)(u >> SBITS);
    int pos = atomicAdd(&cur[dloc], 1);  // LDS cursor
    int d = n0 + dloc;
    colw[base + pos] = pack_cw(s2, dis[s2] * dis[d]);
  }
}

// Pre-swizzle Ws into MFMA B-fragment order per layer
__global__ __launch_bounds__(256) void swz_w(const float* __restrict__ Ws,
                                             ushort* __restrict__ Wsw, int total) {
  int idx = blockIdx.x * 256 + threadIdx.x;
  if (idx >= total) return;
  int l = idx >> 14, r = idx & 16383;
  int j = r & 7, lane = (r >> 3) & 63, kk = (r >> 9) & 3, c = r >> 11;
  int n = c * 16 + (lane & 15);
  int k = kk * 32 + (lane >> 4) * 8 + j;
  Wsw[idx] = f2bf(Ws[l * 16384 + k * HDIM + n]);
}

// ---------------- per-layer kernels (row-major activations) ----------------

// XW = X @ W. Persistent: W staged in LDS once, static grid-stride over 64-row
// tiles. Per-wave private clds region -> ZERO barriers in the tile loop (no
// vmcnt(0) drains); explicit next-tile A prefetch keeps loads in flight under
// MFMA + restage.
template <bool F32IN>
__global__ __launch_bounds__(256) void gemm_kernel(const void* __restrict__ Xin,
                                                   const ushort* __restrict__ Wsw,
                                                   ushort* __restrict__ XW, int N,
                                                   int ntiles) {
  __shared__ ushort wlds[16384];        // 32 KB swizzled W (persistent)
  __shared__ ushort clds[4][16][136];   // per-wave C restage, 272B row stride
  const int t = threadIdx.x;
  {
    const int4* src = (const int4*)Wsw;
    int4* dst = (int4*)wlds;
#pragma unroll
    for (int i = 0; i < 8; ++i) dst[t + 256 * i] = src[t + 256 * i];
  }
  __syncthreads();  // wlds staged (only barrier in the kernel)

  const int wave = t >> 6, lane = t & 63;
  const int kq = lane >> 4, l15 = lane & 15;

  auto loadA = [&](short8* afr, int tile) {
    const int row0 = tile * 64 + wave * 16 + l15;
#pragma unroll
    for (int kk = 0; kk < 4; ++kk) afr[kk] = short8{0, 0, 0, 0, 0, 0, 0, 0};
    if (row0 < N) {
      if constexpr (F32IN) {
        const float* arow = (const float*)Xin + (size_t)row0 * HDIM;
#pragma unroll
        for (int kk = 0; kk < 4; ++kk) {
          float4 x0 = *(const float4*)(arow + kk * 32 + kq * 8);
          float4 x1 = *(const float4*)(arow + kk * 32 + kq * 8 + 4);
          short8 f;
          f[0] = (short)f2bf(x0.x); f[1] = (short)f2bf(x0.y);
          f[2] = (short)f2bf(x0.z); f[3] = (short)f2bf(x0.w);
          f[4] = (short)f2bf(x1.x); f[5] = (short)f2bf(x1.y);
          f[6] = (short)f2bf(x1.z); f[7] = (short)f2bf(x1.w);
          afr[kk] = f;
        }
      } else {
        const short8* arow = (const short8*)((const ushort*)Xin + (size_t)row0 * HDIM);
#pragma unroll
        for (int kk = 0; kk < 4; ++kk) afr[kk] = arow[kk * 4 + kq];
      }
    }
  };

  int tile = blockIdx.x;
  if (tile >= ntiles) return;
  short8 afr[4];
  loadA(afr, tile);

  for (; tile < ntiles; tile += gridDim.x) {
    const int nt = tile + gridDim.x;
    short8 afn[4];
    if (nt < ntiles) loadA(afn, nt);  // prefetch: stays in flight across MFMA

    f32x4 acc[8];
#pragma unroll
    for (int c = 0; c < 8; ++c) acc[c] = f32x4{0.f, 0.f, 0.f, 0.f};
#pragma unroll
    for (int kk = 0; kk < 4; ++kk) {
#pragma unroll
      for (int c = 0; c < 8; ++c) {
        short8 bfr = *(const short8*)(wlds + (((c * 4 + kk) * 64 + lane) << 3));
        acc[c] = __builtin_amdgcn_mfma_f32_16x16x32_bf16(afr[kk], bfr, acc[c], 0, 0, 0);
      }
    }

    // per-wave transpose through private LDS region (intra-wave lgkmcnt only)
#pragma unroll
    for (int c = 0; c < 8; ++c) {
#pragma unroll
      for (int r = 0; r < 4; ++r)
        clds[wave][kq * 4 + r][c * 16 + l15] = f2bf(acc[c][r]);
    }
    // read back coalesced: 16 rows x 16 int4 per wave
    const int grow0 = tile * 64 + wave * 16;
#pragma unroll
    for (int i = 0; i < 4; ++i) {
      int pi = i * 64 + lane;
      int row = pi >> 4, piece = pi & 15;
      if (grow0 + row < N)
        *(int4*)(XW + (size_t)(grow0 + row) * HDIM + piece * 8) =
            *(const int4*)(&clds[wave][row][piece * 8]);
    }
#pragma unroll
    for (int kk = 0; kk < 4; ++kk) afr[kk] = afn[kk];
  }
}

// Aggregation: one node per wave. lane = e*16+c; 16 lanes x uint4 = full 256B
// row per edge, 4 edges per gather instruction, 24 edges in flight per wave
// (bulk issue = max MLP; agg is latency-bound, NOT instruction-bound — r2).
__global__ __launch_bounds__(256, 8) void agg_kernel(const ushort* __restrict__ XW,
                                                     const uint* __restrict__ colw,
                                                     const int* __restrict__ rowptr,
                                                     const float* __restrict__ bias,
                                                     ushort* __restrict__ Y, int N) {
  const int lane = threadIdx.x & 63;
  const int node = blockIdx.x * 4 + (threadIdx.x >> 6);
  if (node >= N) return;
  const int e = lane >> 4, c = lane & 15;
  const int beg = rowptr[node];
  const int pdeg = rowptr[node + 1] - beg;  // multiple of 4, >= 4
  const int last = pdeg - 1;

  uint cw[6];
#pragma unroll
  for (int k = 0; k < 6; ++k) {
    int off = 4 * k + e;
    cw[k] = __builtin_nontemporal_load(colw + beg + (off < pdeg ? off : last));
  }
  uint4 gv[6];
#pragma unroll
  for (int k = 0; k < 6; ++k)
    gv[k] = *(const uint4*)(XW + ((size_t)cw_src(cw[k]) << 7) + c * 8);

  f32x2 acc[4];
#pragma unroll
  for (int i = 0; i < 4; ++i) acc[i] = f32x2{0.f, 0.f};

#pragma unroll
  for (int k = 0; k < 6; ++k) {
    int off = 4 * k + e;
    float w = (off < pdeg) ? cw_w(cw[k]) : 0.f;
    f32x2 wv = f32x2{w, w};
    uint4 v = gv[k];
    acc[0] = __builtin_elementwise_fma(wv, f32x2{bflo(v.x), bfhi(v.x)}, acc[0]);
    acc[1] = __builtin_elementwise_fma(wv, f32x2{bflo(v.y), bfhi(v.y)}, acc[1]);
    acc[2] = __builtin_elementwise_fma(wv, f32x2{bflo(v.z), bfhi(v.z)}, acc[2]);
    acc[3] = __builtin_elementwise_fma(wv, f32x2{bflo(v.w), bfhi(v.w)}, acc[3]);
  }
  // tail for deg > 23 (rare)
  for (int off = 24 + e; off < pdeg; off += 4) {
    uint u = __builtin_nontemporal_load(colw + beg + off);
    uint4 v = *(const uint4*)(XW + ((size_t)cw_src(u) << 7) + c * 8);
    float w = cw_w(u);
    f32x2 wv = f32x2{w, w};
    acc[0] = __builtin_elementwise_fma(wv, f32x2{bflo(v.x), bfhi(v.x)}, acc[0]);
    acc[1] = __builtin_elementwise_fma(wv, f32x2{bflo(v.y), bfhi(v.y)}, acc[1]);
    acc[2] = __builtin_elementwise_fma(wv, f32x2{bflo(v.z), bfhi(v.z)}, acc[2]);
    acc[3] = __builtin_elementwise_fma(wv, f32x2{bflo(v.w), bfhi(v.w)}, acc[3]);
  }

#pragma unroll
  for (int i = 0; i < 4; ++i) {
    acc[i].x += __shfl_xor(acc[i].x, 16, 64);
    acc[i].y += __shfl_xor(acc[i].y, 16, 64);
    acc[i].x += __shfl_xor(acc[i].x, 32, 64);
    acc[i].y += __shfl_xor(acc[i].y, 32, 64);
  }
  if (e == 0) {
    float4 b0 = *(const float4*)(bias + c * 8);
    float4 b1 = *(const float4*)(bias + c * 8 + 4);
    uint4 pk;
    pk.x = (uint)f2bf(fmaxf(acc[0].x + b0.x, 0.f)) | ((uint)f2bf(fmaxf(acc[0].y + b0.y, 0.f)) << 16);
    pk.y = (uint)f2bf(fmaxf(acc[1].x + b0.z, 0.f)) | ((uint)f2bf(fmaxf(acc[1].y + b0.w, 0.f)) << 16);
    pk.z = (uint)f2bf(fmaxf(acc[2].x + b1.x, 0.f)) | ((uint)f2bf(fmaxf(acc[2].y + b1.y, 0.f)) << 16);
    pk.w = (uint)f2bf(fmaxf(acc[3].x + b1.z, 0.f)) | ((uint)f2bf(fmaxf(acc[3].y + b1.w, 0.f)) << 16);
    *(uint4*)(Y + (size_t)node * HDIM + c * 8) = pk;
  }
}

// ---------------- pooling + head ----------------

__global__ __launch_bounds__(256) void pool_partial(const ushort* __restrict__ x,
                                                    const int* __restrict__ batch,
                                                    float* __restrict__ pooled,
                                                    int* __restrict__ gcnt, int N) {
  const int g = blockIdx.x, s = blockIdx.y;  // gridDim.y = 8 splits
  const int t = threadIdx.x;
  __shared__ int range[2];
  __shared__ float sums[256];
  if (t < 2) {
    int target = g + t;
    int lo = 0, hi = N;
    while (lo < hi) {
      int mid = (lo + hi) >> 1;
      if (batch[mid] < target) lo = mid + 1;
      else hi = mid;
    }
    range[t] = lo;
  }
  __syncthreads();
  int beg = range[0], end = range[1];
  if (s == 0 && t == 0) gcnt[g] = end - beg;
  int col = t & 127, half = t >> 7;
  float acc = 0.f;
  for (int n = beg + s * 2 + half; n < end; n += 16) {
    acc += __uint_as_float(((uint)x[(size_t)n * HDIM + col]) << 16);
  }
  sums[t] = acc;
  __syncthreads();
  if (t < 128) atomicAdd(&pooled[g * HDIM + t], sums[t] + sums[t + 128]);
}

__global__ __launch_bounds__(256) void out_final(const float* __restrict__ pooled,
                                                 const int* __restrict__ gcnt,
                                                 const float* __restrict__ W_out,
                                                 const float* __restrict__ b_out,
                                                 float* __restrict__ out, int G, int C) {
  int i = blockIdx.x * 256 + threadIdx.x;
  if (i >= G * C) return;
  int g = i / C, c = i - g * C;
  float inv = 1.f / (float)max(gcnt[g], 1);
  const float* pg = pooled + g * HDIM;
  float o = 0.f;
  for (int h = 0; h < HDIM; ++h) o += pg[h] * W_out[h * C + c];
  out[i] = b_out[c] + o * inv;
}

// ---------------- host ----------------

extern "C" void kernel_launch(void* const* d_in, const int* in_sizes, int n_in,
                              void* d_out, int out_size, void* d_ws, size_t ws_size,
                              hipStream_t stream) {
  (void)n_in;
  (void)ws_size;
  const float* x = (const float*)d_in[0];
  const int* ei = (const int*)d_in[1];
  const int* batch = (const int*)d_in[2];
  const float* Ws = (const float*)d_in[4];
  const float* bs = (const float*)d_in[5];
  const float* W_out = (const float*)d_in[6];
  const float* b_out = (const float*)d_in[7];
  float* out = (float*)d_out;

  const int N = in_sizes[0] / HDIM;
  const int E = in_sizes[1] / 2;
  const int L = in_sizes[5] / HDIM;
  const int C = in_sizes[7];
  const int G = out_size / C;
  const int SB = (N + SBMASK) >> SBITS;      // sub-buckets of 256 nodes
  const int cap = E / SB + 2048;             // per-sub-bucket capacity (~32 sigma)

  char* p = (char*)d_ws;
  auto carve = [&](size_t bytes) {
    char* r = p;
    p += (bytes + 255) & ~(size_t)255;
    return r;
  };
  int* bktcur = (int*)carve(SBMAX * 64);     // one 64B line per counter
  float* dis = (float*)carve((size_t)N * 4);
  int* degs = (int*)carve((size_t)N * 4);
  int* rowptr = (int*)carve((size_t)(N + 1) * 4);
  int* sbtot = (int*)carve(SBMAX * 4);
  int* sbbase = (int*)carve(SBMAX * 4);
  uint* bkt = (uint*)carve((size_t)SB * cap * 4);
  uint* colw = (uint*)carve(((size_t)E + 4 * (size_t)N + 64) * 4);
  ushort* Wsw = (ushort*)carve((size_t)L * HDIM * HDIM * 2);
  ushort* xw = (ushort*)carve((size_t)N * HDIM * 2);
  ushort* y0 = (ushort*)carve((size_t)N * HDIM * 2);
  ushort* y1 = (ushort*)carve((size_t)N * HDIM * 2);
  float* pooled = (float*)carve((size_t)G * HDIM * 4 + (size_t)G * 4);
  int* gcnt = (int*)(pooled + (size_t)G * HDIM);

  hipMemsetAsync(bktcur, 0, SBMAX * 64, stream);
  hipMemsetAsync(pooled, 0, (size_t)G * HDIM * 4 + (size_t)G * 4, stream);

  bucket_edges<<<(E + 2047) / 2048, 256, 0, stream>>>(ei, bktcur, bkt, E, cap);
  csr_count<<<SB, 256, 0, stream>>>(bkt, bktcur, dis, degs, sbtot, cap, N);
  scan_sb<<<1, SBMAX, 0, stream>>>(sbtot, sbbase, rowptr, SB, N);
  csr_place<<<SB, 256, 0, stream>>>(bkt, bktcur, sbbase, dis, degs, rowptr, colw, cap, N);
  swz_w<<<(L * HDIM * HDIM + 255) / 256, 256, 0, stream>>>(Ws, Wsw, L * HDIM * HDIM);

  const int ntiles = (N + 63) / 64;
  const int gb = 768;  // persistent: 3 blocks/CU (49 KB LDS)
  gemm_kernel<true><<<gb, 256, 0, stream>>>(x, Wsw, xw, N, ntiles);
  agg_kernel<<<(N + 3) / 4, 256, 0, stream>>>(xw, colw, rowptr, bs, y0, N);
  ushort* xc = y0;
  ushort* xn = y1;
  for (int l = 1; l < L; ++l) {
    gemm_kernel<false><<<gb, 256, 0, stream>>>(xc, Wsw + (size_t)l * HDIM * HDIM, xw, N, ntiles);
    agg_kernel<<<(N + 3) / 4, 256, 0, stream>>>(xw, colw, rowptr, bs + (size_t)l * HDIM, xn, N);
    ushort* tmp = xc;
    xc = xn;
    xn = tmp;
  }
  pool_partial<<<dim3(G, 8), 256, 0, stream>>>(xc, batch, pooled, gcnt, N);
  out_final<<<(G * C + 255) / 256, 256, 0, stream>>>(pooled, gcnt, W_out, b_out, out, G, C);
}

// Round 4
// 553.170 us; speedup vs baseline: 1.2052x; 1.0303x over previous
//
#include <hip/hip_runtime.h>
#include <hip/hip_bf16.h>
#include <stdint.h>

#define HDIM 128
#define SBITS 8
#define SBMASK 255
#define SBMAX 512  // supports N <= 131072

typedef __attribute__((ext_vector_type(8))) short short8;
typedef __attribute__((ext_vector_type(4))) float f32x4;
typedef __attribute__((ext_vector_type(2))) float f32x2;

__device__ __forceinline__ ushort f2bf(float f) {
  uint u = __float_as_uint(f);
  u = (u + 0x7fffu + ((u >> 16) & 1u)) >> 16;
  return (ushort)u;
}
__device__ __forceinline__ float bflo(uint v) { return __uint_as_float(v << 16); }
__device__ __forceinline__ float bfhi(uint v) { return __uint_as_float(v & 0xffff0000u); }

// padded degree: deg = cnt+1 padded to multiple of 4
__device__ __forceinline__ int pdeg4(int c) { return (c + 4) & ~3; }

// packed colw entry: src (17 bits) | bf15 weight << 17 (weight in (0,1])
__device__ __forceinline__ uint pack_cw(int src, float w) {
  uint w15 = (__float_as_uint(w) + 0x8000u) >> 16;
  return (uint)src | (w15 << 17);
}
__device__ __forceinline__ uint cw_src(uint u) { return u & 0x1FFFFu; }
__device__ __forceinline__ float cw_w(uint u) { return __uint_as_float((u >> 17) << 16); }

// ---------------- setup: CSR build with zero global RMW hotspots ----------------

// Edge stream -> SB sub-buckets of 256 dst nodes. Entry: d_local(8b)|src<<8.
// LDS-hist ranking; ONE allocator atomic per sub-bucket per block.
__global__ __launch_bounds__(256) void bucket_edges(const int* __restrict__ ei,
                                                    int* __restrict__ bktcur,
                                                    uint* __restrict__ bkt, int E,
                                                    int cap) {
  __shared__ int hist[SBMAX], base[SBMAX];
  const int t = threadIdx.x;
  const int c0 = blockIdx.x * 2048;
  for (int i = t; i < SBMAX; i += 256) hist[i] = 0;
  __syncthreads();
  uint pk[8];
  int sb_[8], rk[8];
#pragma unroll
  for (int j = 0; j < 8; ++j) {
    int idx = c0 + j * 256 + t;
    sb_[j] = -1;
    if (idx < E) {
      int s = ei[idx];
      int d = ei[E + idx];
      int b = d >> SBITS;
      pk[j] = (uint)(d & SBMASK) | ((uint)s << SBITS);
      sb_[j] = b;
      rk[j] = atomicAdd(&hist[b], 1);
    }
  }
  __syncthreads();
  for (int i = t; i < SBMAX; i += 256)
    base[i] = hist[i] ? atomicAdd(&bktcur[i * 16], hist[i]) : 0;
  __syncthreads();
#pragma unroll
  for (int j = 0; j < 8; ++j)
    if (sb_[j] >= 0)
      bkt[(size_t)sb_[j] * cap + base[sb_[j]] + rk[j]] = pk[j];
}

// One block owns one 256-node sub-bucket: LDS count -> dis + degs + padded total.
__global__ __launch_bounds__(256) void csr_count(const uint* __restrict__ bkt,
                                                 const int* __restrict__ bktcur,
                                                 float* __restrict__ dis,
                                                 int* __restrict__ degs,
                                                 int* __restrict__ sbtot, int cap,
                                                 int N) {
  __shared__ int cnt[256];
  __shared__ int red[256];
  const int sb = blockIdx.x, t = threadIdx.x;
  const int n0 = sb << SBITS;
  const int ecnt = bktcur[sb * 16];
  const uint* eb = bkt + (size_t)sb * cap;
  cnt[t] = 0;
  __syncthreads();
  for (int i = t; i < ecnt; i += 256)
    atomicAdd(&cnt[__builtin_nontemporal_load(eb + i) & SBMASK], 1);
  __syncthreads();
  int s = 0;
  const int n = n0 + t;
  if (n < N) {
    int c = cnt[t];
    degs[n] = c;
    dis[n] = rsqrtf((float)(c + 1));
    s = pdeg4(c);
  }
  red[t] = s;
  __syncthreads();
  for (int off = 128; off; off >>= 1) {
    if (t < off) red[t] += red[t + off];
    __syncthreads();
  }
  if (t == 0) sbtot[sb] = red[0];
}

// Exclusive scan of SB sub-bucket totals (SB <= 512); also writes rowptr[N].
__global__ __launch_bounds__(512) void scan_sb(const int* __restrict__ sbtot,
                                               int* __restrict__ sbbase,
                                               int* __restrict__ rowptr, int SB,
                                               int N) {
  __shared__ int sh[SBMAX];
  int t = threadIdx.x;
  int v = (t < SB) ? sbtot[t] : 0;
  sh[t] = v;
  __syncthreads();
  for (int off = 1; off < SBMAX; off <<= 1) {
    int add = (t >= off) ? sh[t - off] : 0;
    __syncthreads();
    sh[t] += add;
    __syncthreads();
  }
  if (t < SB) sbbase[t] = sh[t] - v;
  if (t == SBMAX - 1) rowptr[N] = sh[SBMAX - 1];
}

// One block owns one sub-bucket: load degs (no recount), LDS prefix, write
// rowptr (coalesced), place self-loop/pads/edges via LDS cursors. NO global
// atomics; one writer CU per colw range.
__global__ __launch_bounds__(256) void csr_place(const uint* __restrict__ bkt,
                                                 const int* __restrict__ bktcur,
                                                 const int* __restrict__ sbbase,
                                                 const float* __restrict__ dis,
                                                 const int* __restrict__ degs,
                                                 int* __restrict__ rowptr,
                                                 uint* __restrict__ colw, int cap,
                                                 int N) {
  __shared__ int cur[256];
  __shared__ int sh[256];
  const int sb = blockIdx.x, t = threadIdx.x;
  const int n0 = sb << SBITS;
  const int ecnt = bktcur[sb * 16];
  const uint* eb = bkt + (size_t)sb * cap;
  const int base = sbbase[sb];
  const int n = n0 + t;
  const int deg = (n < N) ? degs[n] : 0;
  const int v = (n < N) ? pdeg4(deg) : 0;
  sh[t] = v;
  __syncthreads();
  for (int off = 1; off < 256; off <<= 1) {
    int add = (t >= off) ? sh[t - off] : 0;
    __syncthreads();
    sh[t] += add;
    __syncthreads();
  }
  const int p = sh[t] - v;
  if (n < N) {
    rowptr[n] = base + p;
    cur[t] = p + 1;  // self-loop occupies slot p
    float dn = dis[n];
    colw[base + p] = pack_cw(n, dn * dn);
    for (int q = deg + 1; q < v; ++q) colw[base + p + q] = (uint)n;  // pads
  }
  __syncthreads();
  for (int i = t; i < ecnt; i += 256) {
    uint u = __builtin_nontemporal_load(eb + i);
    int dloc = (int)(u & SBMASK);
    int s2 = (int)(u >> SBITS);
    int pos = atomicAdd(&cur[dloc], 1);  // LDS cursor
    int d = n0 + dloc;
    colw[base + pos] = pack_cw(s2, dis[s2] * dis[d]);
  }
}

// Pre-swizzle Ws into MFMA B-fragment order per layer
__global__ __launch_bounds__(256) void swz_w(const float* __restrict__ Ws,
                                             ushort* __restrict__ Wsw, int total) {
  int idx = blockIdx.x * 256 + threadIdx.x;
  if (idx >= total) return;
  int l = idx >> 14, r = idx & 16383;
  int j = r & 7, lane = (r >> 3) & 63, kk = (r >> 9) & 3, c = r >> 11;
  int n = c * 16 + (lane & 15);
  int k = kk * 32 + (lane >> 4) * 8 + j;
  Wsw[idx] = f2bf(Ws[l * 16384 + k * HDIM + n]);
}

// ---------------- per-layer kernels (row-major activations) ----------------

// XW = X @ W. Persistent: W staged in LDS once, static grid-stride over 64-row
// tiles. (Round-1 measured-best form; barrier-free and dynamic-grab variants
// both regressed — implicit wave overlap already hides the barrier drain.)
template <bool F32IN>
__global__ __launch_bounds__(256) void gemm_kernel(const void* __restrict__ Xin,
                                                   const ushort* __restrict__ Wsw,
                                                   ushort* __restrict__ XW, int N,
                                                   int ntiles) {
  __shared__ ushort wlds[16384];    // 32 KB swizzled W (persistent)
  __shared__ ushort clds[64 * 136]; // C restage, padded stride
  const int t = threadIdx.x;
  {
    const int4* src = (const int4*)Wsw;
    int4* dst = (int4*)wlds;
#pragma unroll
    for (int i = 0; i < 8; ++i) dst[t + 256 * i] = src[t + 256 * i];
  }
  __syncthreads();

  const int wave = t >> 6, lane = t & 63;
  const int kq = lane >> 4;  // 0..3

  for (int tile = blockIdx.x; tile < ntiles; tile += gridDim.x) {
    const int row0 = tile * 64 + wave * 16 + (lane & 15);
    const bool inb = row0 < N;

    short8 afr[4];
#pragma unroll
    for (int kk = 0; kk < 4; ++kk) afr[kk] = short8{0, 0, 0, 0, 0, 0, 0, 0};
    if (inb) {
      if constexpr (F32IN) {
        const float* arow = (const float*)Xin + (size_t)row0 * HDIM;
#pragma unroll
        for (int kk = 0; kk < 4; ++kk) {
          float4 x0 = *(const float4*)(arow + kk * 32 + kq * 8);
          float4 x1 = *(const float4*)(arow + kk * 32 + kq * 8 + 4);
          short8 f;
          f[0] = (short)f2bf(x0.x); f[1] = (short)f2bf(x0.y);
          f[2] = (short)f2bf(x0.z); f[3] = (short)f2bf(x0.w);
          f[4] = (short)f2bf(x1.x); f[5] = (short)f2bf(x1.y);
          f[6] = (short)f2bf(x1.z); f[7] = (short)f2bf(x1.w);
          afr[kk] = f;
        }
      } else {
        const short8* arow = (const short8*)((const ushort*)Xin + (size_t)row0 * HDIM);
#pragma unroll
        for (int kk = 0; kk < 4; ++kk) afr[kk] = arow[kk * 4 + kq];
      }
    }

    f32x4 acc[8];
#pragma unroll
    for (int c = 0; c < 8; ++c) acc[c] = f32x4{0.f, 0.f, 0.f, 0.f};
#pragma unroll
    for (int kk = 0; kk < 4; ++kk) {
#pragma unroll
      for (int c = 0; c < 8; ++c) {
        short8 bfr = *(const short8*)(wlds + (((c * 4 + kk) * 64 + lane) << 3));
        acc[c] = __builtin_amdgcn_mfma_f32_16x16x32_bf16(afr[kk], bfr, acc[c], 0, 0, 0);
      }
    }

    __syncthreads();  // previous tile's clds readers done
    const int m0 = wave * 16 + kq * 4;
#pragma unroll
    for (int c = 0; c < 8; ++c) {
      int col = c * 16 + (lane & 15);
#pragma unroll
      for (int r = 0; r < 4; ++r) clds[(m0 + r) * 136 + col] = f2bf(acc[c][r]);
    }
    __syncthreads();
    // coalesced store: 64 rows x 16 int4
#pragma unroll
    for (int i = 0; i < 4; ++i) {
      int idx = t + 256 * i;
      int row = idx >> 4, piece = idx & 15;
      int grow = tile * 64 + row;
      if (grow < N)
        ((int4*)XW)[(size_t)tile * 1024 + idx] =
            *(const int4*)(clds + row * 136 + piece * 8);
    }
  }
}

// Aggregation: one node per wave. lane = e*16+c; 16 lanes x uint4 = full 256B
// row per edge, 4 edges per gather instruction, 24 edges per wave issued in
// ONE bulk block. launch_bounds(256,3) -> ~170 VGPR cap so all 24 uint4 stay
// in registers/in flight (at (256,8) the 64-VGPR cap forced the compiler to
// chunk the gathers ~6 at a time -> MLP starvation; VGPR_Count=32 proved it).
__global__ __launch_bounds__(256, 3) void agg_kernel(const ushort* __restrict__ XW,
                                                     const uint* __restrict__ colw,
                                                     const int* __restrict__ rowptr,
                                                     const float* __restrict__ bias,
                                                     ushort* __restrict__ Y, int N) {
  const int lane = threadIdx.x & 63;
  const int node = blockIdx.x * 4 + (threadIdx.x >> 6);
  if (node >= N) return;
  const int e = lane >> 4, c = lane & 15;
  const int beg = rowptr[node];
  const int pdeg = rowptr[node + 1] - beg;  // multiple of 4, >= 4
  const int last = pdeg - 1;

  uint cw[6];
#pragma unroll
  for (int k = 0; k < 6; ++k) {
    int off = 4 * k + e;
    cw[k] = __builtin_nontemporal_load(colw + beg + (off < pdeg ? off : last));
  }
  uint4 gv[6];
#pragma unroll
  for (int k = 0; k < 6; ++k)
    gv[k] = *(const uint4*)(XW + ((size_t)cw_src(cw[k]) << 7) + c * 8);

  f32x2 acc[4];
#pragma unroll
  for (int i = 0; i < 4; ++i) acc[i] = f32x2{0.f, 0.f};

#pragma unroll
  for (int k = 0; k < 6; ++k) {
    int off = 4 * k + e;
    float w = (off < pdeg) ? cw_w(cw[k]) : 0.f;
    f32x2 wv = f32x2{w, w};
    uint4 v = gv[k];
    acc[0] = __builtin_elementwise_fma(wv, f32x2{bflo(v.x), bfhi(v.x)}, acc[0]);
    acc[1] = __builtin_elementwise_fma(wv, f32x2{bflo(v.y), bfhi(v.y)}, acc[1]);
    acc[2] = __builtin_elementwise_fma(wv, f32x2{bflo(v.z), bfhi(v.z)}, acc[2]);
    acc[3] = __builtin_elementwise_fma(wv, f32x2{bflo(v.w), bfhi(v.w)}, acc[3]);
  }
  // tail for deg > 23 (rare)
  for (int off = 24 + e; off < pdeg; off += 4) {
    uint u = __builtin_nontemporal_load(colw + beg + off);
    uint4 v = *(const uint4*)(XW + ((size_t)cw_src(u) << 7) + c * 8);
    float w = cw_w(u);
    f32x2 wv = f32x2{w, w};
    acc[0] = __builtin_elementwise_fma(wv, f32x2{bflo(v.x), bfhi(v.x)}, acc[0]);
    acc[1] = __builtin_elementwise_fma(wv, f32x2{bflo(v.y), bfhi(v.y)}, acc[1]);
    acc[2] = __builtin_elementwise_fma(wv, f32x2{bflo(v.z), bfhi(v.z)}, acc[2]);
    acc[3] = __builtin_elementwise_fma(wv, f32x2{bflo(v.w), bfhi(v.w)}, acc[3]);
  }

#pragma unroll
  for (int i = 0; i < 4; ++i) {
    acc[i].x += __shfl_xor(acc[i].x, 16, 64);
    acc[i].y += __shfl_xor(acc[i].y, 16, 64);
    acc[i].x += __shfl_xor(acc[i].x, 32, 64);
    acc[i].y += __shfl_xor(acc[i].y, 32, 64);
  }
  if (e == 0) {
    float4 b0 = *(const float4*)(bias + c * 8);
    float4 b1 = *(const float4*)(bias + c * 8 + 4);
    uint4 pk;
    pk.x = (uint)f2bf(fmaxf(acc[0].x + b0.x, 0.f)) | ((uint)f2bf(fmaxf(acc[0].y + b0.y, 0.f)) << 16);
    pk.y = (uint)f2bf(fmaxf(acc[1].x + b0.z, 0.f)) | ((uint)f2bf(fmaxf(acc[1].y + b0.w, 0.f)) << 16);
    pk.z = (uint)f2bf(fmaxf(acc[2].x + b1.x, 0.f)) | ((uint)f2bf(fmaxf(acc[2].y + b1.y, 0.f)) << 16);
    pk.w = (uint)f2bf(fmaxf(acc[3].x + b1.z, 0.f)) | ((uint)f2bf(fmaxf(acc[3].y + b1.w, 0.f)) << 16);
    *(uint4*)(Y + (size_t)node * HDIM + c * 8) = pk;
  }
}

// ---------------- pooling + head ----------------

__global__ __launch_bounds__(256) void pool_partial(const ushort* __restrict__ x,
                                                    const int* __restrict__ batch,
                                                    float* __restrict__ pooled,
                                                    int* __restrict__ gcnt, int N) {
  const int g = blockIdx.x, s = blockIdx.y;  // gridDim.y = 8 splits
  const int t = threadIdx.x;
  __shared__ int range[2];
  __shared__ float sums[256];
  if (t < 2) {
    int target = g + t;
    int lo = 0, hi = N;
    while (lo < hi) {
      int mid = (lo + hi) >> 1;
      if (batch[mid] < target) lo = mid + 1;
      else hi = mid;
    }
    range[t] = lo;
  }
  __syncthreads();
  int beg = range[0], end = range[1];
  if (s == 0 && t == 0) gcnt[g] = end - beg;
  int col = t & 127, half = t >> 7;
  float acc = 0.f;
  for (int n = beg + s * 2 + half; n < end; n += 16) {
    acc += __uint_as_float(((uint)x[(size_t)n * HDIM + col]) << 16);
  }
  sums[t] = acc;
  __syncthreads();
  if (t < 128) atomicAdd(&pooled[g * HDIM + t], sums[t] + sums[t + 128]);
}

__global__ __launch_bounds__(256) void out_final(const float* __restrict__ pooled,
                                                 const int* __restrict__ gcnt,
                                                 const float* __restrict__ W_out,
                                                 const float* __restrict__ b_out,
                                                 float* __restrict__ out, int G, int C) {
  int i = blockIdx.x * 256 + threadIdx.x;
  if (i >= G * C) return;
  int g = i / C, c = i - g * C;
  float inv = 1.f / (float)max(gcnt[g], 1);
  const float* pg = pooled + g * HDIM;
  float o = 0.f;
  for (int h = 0; h < HDIM; ++h) o += pg[h] * W_out[h * C + c];
  out[i] = b_out[c] + o * inv;
}

// ---------------- host ----------------

extern "C" void kernel_launch(void* const* d_in, const int* in_sizes, int n_in,
                              void* d_out, int out_size, void* d_ws, size_t ws_size,
                              hipStream_t stream) {
  (void)n_in;
  (void)ws_size;
  const float* x = (const float*)d_in[0];
  const int* ei = (const int*)d_in[1];
  const int* batch = (const int*)d_in[2];
  const float* Ws = (const float*)d_in[4];
  const float* bs = (const float*)d_in[5];
  const float* W_out = (const float*)d_in[6];
  const float* b_out = (const float*)d_in[7];
  float* out = (float*)d_out;

  const int N = in_sizes[0] / HDIM;
  const int E = in_sizes[1] / 2;
  const int L = in_sizes[5] / HDIM;
  const int C = in_sizes[7];
  const int G = out_size / C;
  const int SB = (N + SBMASK) >> SBITS;      // sub-buckets of 256 nodes
  const int cap = E / SB + 2048;             // per-sub-bucket capacity (~32 sigma)

  char* p = (char*)d_ws;
  auto carve = [&](size_t bytes) {
    char* r = p;
    p += (bytes + 255) & ~(size_t)255;
    return r;
  };
  int* bktcur = (int*)carve(SBMAX * 64);     // one 64B line per counter
  float* dis = (float*)carve((size_t)N * 4);
  int* degs = (int*)carve((size_t)N * 4);
  int* rowptr = (int*)carve((size_t)(N + 1) * 4);
  int* sbtot = (int*)carve(SBMAX * 4);
  int* sbbase = (int*)carve(SBMAX * 4);
  uint* bkt = (uint*)carve((size_t)SB * cap * 4);
  uint* colw = (uint*)carve(((size_t)E + 4 * (size_t)N + 64) * 4);
  ushort* Wsw = (ushort*)carve((size_t)L * HDIM * HDIM * 2);
  ushort* xw = (ushort*)carve((size_t)N * HDIM * 2);
  ushort* y0 = (ushort*)carve((size_t)N * HDIM * 2);
  ushort* y1 = (ushort*)carve((size_t)N * HDIM * 2);
  float* pooled = (float*)carve((size_t)G * HDIM * 4 + (size_t)G * 4);
  int* gcnt = (int*)(pooled + (size_t)G * HDIM);

  hipMemsetAsync(bktcur, 0, SBMAX * 64, stream);
  hipMemsetAsync(pooled, 0, (size_t)G * HDIM * 4 + (size_t)G * 4, stream);

  bucket_edges<<<(E + 2047) / 2048, 256, 0, stream>>>(ei, bktcur, bkt, E, cap);
  csr_count<<<SB, 256, 0, stream>>>(bkt, bktcur, dis, degs, sbtot, cap, N);
  scan_sb<<<1, SBMAX, 0, stream>>>(sbtot, sbbase, rowptr, SB, N);
  csr_place<<<SB, 256, 0, stream>>>(bkt, bktcur, sbbase, dis, degs, rowptr, colw, cap, N);
  swz_w<<<(L * HDIM * HDIM + 255) / 256, 256, 0, stream>>>(Ws, Wsw, L * HDIM * HDIM);

  const int ntiles = (N + 63) / 64;
  const int gb = 768;  // persistent: 3 blocks/CU (49.4 KB LDS)
  gemm_kernel<true><<<gb, 256, 0, stream>>>(x, Wsw, xw, N, ntiles);
  agg_kernel<<<(N + 3) / 4, 256, 0, stream>>>(xw, colw, rowptr, bs, y0, N);
  ushort* xc = y0;
  ushort* xn = y1;
  for (int l = 1; l < L; ++l) {
    gemm_kernel<false><<<gb, 256, 0, stream>>>(xc, Wsw + (size_t)l * HDIM * HDIM, xw, N, ntiles);
    agg_kernel<<<(N + 3) / 4, 256, 0, stream>>>(xw, colw, rowptr, bs + (size_t)l * HDIM, xn, N);
    ushort* tmp = xc;
    xc = xn;
    xn = tmp;
  }
  pool_partial<<<dim3(G, 8), 256, 0, stream>>>(xc, batch, pooled, gcnt, N);
  out_final<<<(G * C + 255) / 256, 256, 0, stream>>>(pooled, gcnt, W_out, b_out, out, G, C);
}

// Round 5
// 542.638 us; speedup vs baseline: 1.2286x; 1.0194x over previous
//
#include <hip/hip_runtime.h>
#include <hip/hip_bf16.h>
#include <stdint.h>

#define HDIM 128
#define SBITS 8
#define SBMASK 255
#define SBMAX 512  // supports N <= 131072

typedef __attribute__((ext_vector_type(8))) short short8;
typedef __attribute__((ext_vector_type(4))) float f32x4;
typedef __attribute__((ext_vector_type(2))) float f32x2;

__device__ __forceinline__ ushort f2bf(float f) {
  uint u = __float_as_uint(f);
  u = (u + 0x7fffu + ((u >> 16) & 1u)) >> 16;
  return (ushort)u;
}
__device__ __forceinline__ float bflo(uint v) { return __uint_as_float(v << 16); }
__device__ __forceinline__ float bfhi(uint v) { return __uint_as_float(v & 0xffff0000u); }

// padded degree: deg = cnt+1 padded to multiple of 4
__device__ __forceinline__ int pdeg4(int c) { return (c + 4) & ~3; }

// packed colw entry: src (17 bits) | bf15 weight << 17 (weight in (0,1])
// pads are stored as plain (uint)n -> weight bits 0 -> w == 0.0f
__device__ __forceinline__ uint pack_cw(int src, float w) {
  uint w15 = (__float_as_uint(w) + 0x8000u) >> 16;
  return (uint)src | (w15 << 17);
}
__device__ __forceinline__ uint cw_src(uint u) { return u & 0x1FFFFu; }
__device__ __forceinline__ float cw_w(uint u) { return __uint_as_float((u >> 17) << 16); }

// ---------------- setup: CSR build with zero global RMW hotspots ----------------

// Edge stream -> SB sub-buckets of 256 dst nodes. Entry: d_local(8b)|src<<8.
// LDS-hist ranking; ONE allocator atomic per sub-bucket per block.
__global__ __launch_bounds__(256) void bucket_edges(const int* __restrict__ ei,
                                                    int* __restrict__ bktcur,
                                                    uint* __restrict__ bkt, int E,
                                                    int cap) {
  __shared__ int hist[SBMAX], base[SBMAX];
  const int t = threadIdx.x;
  const int c0 = blockIdx.x * 2048;
  for (int i = t; i < SBMAX; i += 256) hist[i] = 0;
  __syncthreads();
  uint pk[8];
  int sb_[8], rk[8];
#pragma unroll
  for (int j = 0; j < 8; ++j) {
    int idx = c0 + j * 256 + t;
    sb_[j] = -1;
    if (idx < E) {
      int s = ei[idx];
      int d = ei[E + idx];
      int b = d >> SBITS;
      pk[j] = (uint)(d & SBMASK) | ((uint)s << SBITS);
      sb_[j] = b;
      rk[j] = atomicAdd(&hist[b], 1);
    }
  }
  __syncthreads();
  for (int i = t; i < SBMAX; i += 256)
    base[i] = hist[i] ? atomicAdd(&bktcur[i * 16], hist[i]) : 0;
  __syncthreads();
#pragma unroll
  for (int j = 0; j < 8; ++j)
    if (sb_[j] >= 0)
      bkt[(size_t)sb_[j] * cap + base[sb_[j]] + rk[j]] = pk[j];
}

// One block owns one 256-node sub-bucket: LDS count -> dis + degs + padded total.
__global__ __launch_bounds__(256) void csr_count(const uint* __restrict__ bkt,
                                                 const int* __restrict__ bktcur,
                                                 float* __restrict__ dis,
                                                 int* __restrict__ degs,
                                                 int* __restrict__ sbtot, int cap,
                                                 int N) {
  __shared__ int cnt[256];
  __shared__ int red[256];
  const int sb = blockIdx.x, t = threadIdx.x;
  const int n0 = sb << SBITS;
  const int ecnt = bktcur[sb * 16];
  const uint* eb = bkt + (size_t)sb * cap;
  cnt[t] = 0;
  __syncthreads();
  for (int i = t; i < ecnt; i += 256)
    atomicAdd(&cnt[__builtin_nontemporal_load(eb + i) & SBMASK], 1);
  __syncthreads();
  int s = 0;
  const int n = n0 + t;
  if (n < N) {
    int c = cnt[t];
    degs[n] = c;
    dis[n] = rsqrtf((float)(c + 1));
    s = pdeg4(c);
  }
  red[t] = s;
  __syncthreads();
  for (int off = 128; off; off >>= 1) {
    if (t < off) red[t] += red[t + off];
    __syncthreads();
  }
  if (t == 0) sbtot[sb] = red[0];
}

// Exclusive scan of SB sub-bucket totals (SB <= 512); also writes rowptr[N].
__global__ __launch_bounds__(512) void scan_sb(const int* __restrict__ sbtot,
                                               int* __restrict__ sbbase,
                                               int* __restrict__ rowptr, int SB,
                                               int N) {
  __shared__ int sh[SBMAX];
  int t = threadIdx.x;
  int v = (t < SB) ? sbtot[t] : 0;
  sh[t] = v;
  __syncthreads();
  for (int off = 1; off < SBMAX; off <<= 1) {
    int add = (t >= off) ? sh[t - off] : 0;
    __syncthreads();
    sh[t] += add;
    __syncthreads();
  }
  if (t < SB) sbbase[t] = sh[t] - v;
  if (t == SBMAX - 1) rowptr[N] = sh[SBMAX - 1];
}

// One block owns one sub-bucket: load degs (no recount), LDS prefix, write
// rowptr (coalesced), place self-loop/pads/edges via LDS cursors. NO global
// atomics; one writer CU per colw range.
__global__ __launch_bounds__(256) void csr_place(const uint* __restrict__ bkt,
                                                 const int* __restrict__ bktcur,
                                                 const int* __restrict__ sbbase,
                                                 const float* __restrict__ dis,
                                                 const int* __restrict__ degs,
                                                 int* __restrict__ rowptr,
                                                 uint* __restrict__ colw, int cap,
                                                 int N) {
  __shared__ int cur[256];
  __shared__ int sh[256];
  const int sb = blockIdx.x, t = threadIdx.x;
  const int n0 = sb << SBITS;
  const int ecnt = bktcur[sb * 16];
  const uint* eb = bkt + (size_t)sb * cap;
  const int base = sbbase[sb];
  const int n = n0 + t;
  const int deg = (n < N) ? degs[n] : 0;
  const int v = (n < N) ? pdeg4(deg) : 0;
  sh[t] = v;
  __syncthreads();
  for (int off = 1; off < 256; off <<= 1) {
    int add = (t >= off) ? sh[t - off] : 0;
    __syncthreads();
    sh[t] += add;
    __syncthreads();
  }
  const int p = sh[t] - v;
  if (n < N) {
    rowptr[n] = base + p;
    cur[t] = p + 1;  // self-loop occupies slot p
    float dn = dis[n];
    colw[base + p] = pack_cw(n, dn * dn);
    for (int q = deg + 1; q < v; ++q) colw[base + p + q] = (uint)n;  // pads (w=0)
  }
  __syncthreads();
  for (int i = t; i < ecnt; i += 256) {
    uint u = __builtin_nontemporal_load(eb + i);
    int dloc = (int)(u & SBMASK);
    int s2 = (int)(u >> SBITS);
    int pos = atomicAdd(&cur[dloc], 1);  // LDS cursor
    int d = n0 + dloc;
    colw[base + pos] = pack_cw(s2, dis[s2] * dis[d]);
  }
}

// Pre-swizzle Ws into MFMA B-fragment order per layer
__global__ __launch_bounds__(256) void swz_w(const float* __restrict__ Ws,
                                             ushort* __restrict__ Wsw, int total) {
  int idx = blockIdx.x * 256 + threadIdx.x;
  if (idx >= total) return;
  int l = idx >> 14, r = idx & 16383;
  int j = r & 7, lane = (r >> 3) & 63, kk = (r >> 9) & 3, c = r >> 11;
  int n = c * 16 + (lane & 15);
  int k = kk * 32 + (lane >> 4) * 8 + j;
  Wsw[idx] = f2bf(Ws[l * 16384 + k * HDIM + n]);
}

// ---------------- per-layer kernels (row-major activations) ----------------

// XW = X @ W. Persistent: W staged in LDS once, static grid-stride over 64-row
// tiles. (Round-1 measured-best form.)
template <bool F32IN>
__global__ __launch_bounds__(256) void gemm_kernel(const void* __restrict__ Xin,
                                                   const ushort* __restrict__ Wsw,
                                                   ushort* __restrict__ XW, int N,
                                                   int ntiles) {
  __shared__ ushort wlds[16384];    // 32 KB swizzled W (persistent)
  __shared__ ushort clds[64 * 136]; // C restage, padded stride
  const int t = threadIdx.x;
  {
    const int4* src = (const int4*)Wsw;
    int4* dst = (int4*)wlds;
#pragma unroll
    for (int i = 0; i < 8; ++i) dst[t + 256 * i] = src[t + 256 * i];
  }
  __syncthreads();

  const int wave = t >> 6, lane = t & 63;
  const int kq = lane >> 4;  // 0..3

  for (int tile = blockIdx.x; tile < ntiles; tile += gridDim.x) {
    const int row0 = tile * 64 + wave * 16 + (lane & 15);
    const bool inb = row0 < N;

    short8 afr[4];
#pragma unroll
    for (int kk = 0; kk < 4; ++kk) afr[kk] = short8{0, 0, 0, 0, 0, 0, 0, 0};
    if (inb) {
      if constexpr (F32IN) {
        const float* arow = (const float*)Xin + (size_t)row0 * HDIM;
#pragma unroll
        for (int kk = 0; kk < 4; ++kk) {
          float4 x0 = *(const float4*)(arow + kk * 32 + kq * 8);
          float4 x1 = *(const float4*)(arow + kk * 32 + kq * 8 + 4);
          short8 f;
          f[0] = (short)f2bf(x0.x); f[1] = (short)f2bf(x0.y);
          f[2] = (short)f2bf(x0.z); f[3] = (short)f2bf(x0.w);
          f[4] = (short)f2bf(x1.x); f[5] = (short)f2bf(x1.y);
          f[6] = (short)f2bf(x1.z); f[7] = (short)f2bf(x1.w);
          afr[kk] = f;
        }
      } else {
        const short8* arow = (const short8*)((const ushort*)Xin + (size_t)row0 * HDIM);
#pragma unroll
        for (int kk = 0; kk < 4; ++kk) afr[kk] = arow[kk * 4 + kq];
      }
    }

    f32x4 acc[8];
#pragma unroll
    for (int c = 0; c < 8; ++c) acc[c] = f32x4{0.f, 0.f, 0.f, 0.f};
#pragma unroll
    for (int kk = 0; kk < 4; ++kk) {
#pragma unroll
      for (int c = 0; c < 8; ++c) {
        short8 bfr = *(const short8*)(wlds + (((c * 4 + kk) * 64 + lane) << 3));
        acc[c] = __builtin_amdgcn_mfma_f32_16x16x32_bf16(afr[kk], bfr, acc[c], 0, 0, 0);
      }
    }

    __syncthreads();  // previous tile's clds readers done
    const int m0 = wave * 16 + kq * 4;
#pragma unroll
    for (int c = 0; c < 8; ++c) {
      int col = c * 16 + (lane & 15);
#pragma unroll
      for (int r = 0; r < 4; ++r) clds[(m0 + r) * 136 + col] = f2bf(acc[c][r]);
    }
    __syncthreads();
    // coalesced store: 64 rows x 16 int4
#pragma unroll
    for (int i = 0; i < 4; ++i) {
      int idx = t + 256 * i;
      int row = idx >> 4, piece = idx & 15;
      int grow = tile * 64 + row;
      if (grow < N)
        ((int4*)XW)[(size_t)tile * 1024 + idx] =
            *(const int4*)(clds + row * 136 + piece * 8);
    }
  }
}

// ---------------- aggregation ----------------

// Bulk gather-accumulate of K 4-edge batches. CLAMP=false requires 4*K <= pdeg
// (offsets all in range; pads carry w=0 so no weight masking needed).
template <int K, bool CLAMP>
__device__ __forceinline__ void agg_bulk(const ushort* __restrict__ XW,
                                         const uint* __restrict__ colw, int beg,
                                         int pdeg, int e, int c, f32x2* acc) {
  const int last = pdeg - 1;
  uint cw[K];
#pragma unroll
  for (int k = 0; k < K; ++k) {
    int off = 4 * k + e;
    if (CLAMP) off = off < pdeg ? off : last;
    cw[k] = __builtin_nontemporal_load(colw + beg + off);
  }
  uint4 gv[K];
#pragma unroll
  for (int k = 0; k < K; ++k)
    gv[k] = *(const uint4*)(XW + ((size_t)cw_src(cw[k]) << 7) + c * 8);
#pragma unroll
  for (int k = 0; k < K; ++k) {
    float w;
    if (CLAMP) {
      int off = 4 * k + e;
      w = (off < pdeg) ? cw_w(cw[k]) : 0.f;
    } else {
      w = cw_w(cw[k]);
    }
    f32x2 wv = f32x2{w, w};
    uint4 v = gv[k];
    acc[0] = __builtin_elementwise_fma(wv, f32x2{bflo(v.x), bfhi(v.x)}, acc[0]);
    acc[1] = __builtin_elementwise_fma(wv, f32x2{bflo(v.y), bfhi(v.y)}, acc[1]);
    acc[2] = __builtin_elementwise_fma(wv, f32x2{bflo(v.z), bfhi(v.z)}, acc[2]);
    acc[3] = __builtin_elementwise_fma(wv, f32x2{bflo(v.w), bfhi(v.w)}, acc[3]);
  }
}

// Aggregation: one node per wave. lane = e*16+c; 16 lanes x uint4 = full 256B
// row per edge, 4 edges per gather instruction. nb = pdeg/4 is WAVE-UNIFORM
// (one node per wave) -> branch to exact-size bulk paths 4/5/6: 21% fewer
// gather instructions/line-touches than fixed-6, full MLP preserved (round-2's
// serialized exact-count variant regressed; this one stays bulk).
__global__ __launch_bounds__(256, 3) void agg_kernel(const ushort* __restrict__ XW,
                                                     const uint* __restrict__ colw,
                                                     const int* __restrict__ rowptr,
                                                     const float* __restrict__ bias,
                                                     ushort* __restrict__ Y, int N) {
  const int lane = threadIdx.x & 63;
  const int node = blockIdx.x * 4 + (threadIdx.x >> 6);
  if (node >= N) return;
  const int e = lane >> 4, c = lane & 15;
  const int beg = rowptr[node];
  const int pdeg = rowptr[node + 1] - beg;  // multiple of 4, >= 4
  const int nb = pdeg >> 2;

  f32x2 acc[4];
#pragma unroll
  for (int i = 0; i < 4; ++i) acc[i] = f32x2{0.f, 0.f};

  // wave-uniform dispatch, ordered by probability (deg ~ Poisson(16)):
  if (nb == 4) {                       // ~47%
    agg_bulk<4, false>(XW, colw, beg, pdeg, e, c, acc);
  } else if (nb == 5) {                // ~36%
    agg_bulk<5, false>(XW, colw, beg, pdeg, e, c, acc);
  } else if (nb >= 6) {                // ~17%
    agg_bulk<6, false>(XW, colw, beg, pdeg, e, c, acc);
    for (int off = 24 + e; off < pdeg; off += 4) {  // nb >= 7 tail (rare)
      uint u = __builtin_nontemporal_load(colw + beg + off);
      uint4 v = *(const uint4*)(XW + ((size_t)cw_src(u) << 7) + c * 8);
      float w = cw_w(u);
      f32x2 wv = f32x2{w, w};
      acc[0] = __builtin_elementwise_fma(wv, f32x2{bflo(v.x), bfhi(v.x)}, acc[0]);
      acc[1] = __builtin_elementwise_fma(wv, f32x2{bflo(v.y), bfhi(v.y)}, acc[1]);
      acc[2] = __builtin_elementwise_fma(wv, f32x2{bflo(v.z), bfhi(v.z)}, acc[2]);
      acc[3] = __builtin_elementwise_fma(wv, f32x2{bflo(v.w), bfhi(v.w)}, acc[3]);
    }
  } else {                             // nb <= 3 (~0.2%)
    agg_bulk<4, true>(XW, colw, beg, pdeg, e, c, acc);
  }

#pragma unroll
  for (int i = 0; i < 4; ++i) {
    acc[i].x += __shfl_xor(acc[i].x, 16, 64);
    acc[i].y += __shfl_xor(acc[i].y, 16, 64);
    acc[i].x += __shfl_xor(acc[i].x, 32, 64);
    acc[i].y += __shfl_xor(acc[i].y, 32, 64);
  }
  if (e == 0) {
    float4 b0 = *(const float4*)(bias + c * 8);
    float4 b1 = *(const float4*)(bias + c * 8 + 4);
    uint4 pk;
    pk.x = (uint)f2bf(fmaxf(acc[0].x + b0.x, 0.f)) | ((uint)f2bf(fmaxf(acc[0].y + b0.y, 0.f)) << 16);
    pk.y = (uint)f2bf(fmaxf(acc[1].x + b0.z, 0.f)) | ((uint)f2bf(fmaxf(acc[1].y + b0.w, 0.f)) << 16);
    pk.z = (uint)f2bf(fmaxf(acc[2].x + b1.x, 0.f)) | ((uint)f2bf(fmaxf(acc[2].y + b1.y, 0.f)) << 16);
    pk.w = (uint)f2bf(fmaxf(acc[3].x + b1.z, 0.f)) | ((uint)f2bf(fmaxf(acc[3].y + b1.w, 0.f)) << 16);
    *(uint4*)(Y + (size_t)node * HDIM + c * 8) = pk;
  }
}

// ---------------- pooling + head ----------------

__global__ __launch_bounds__(256) void pool_partial(const ushort* __restrict__ x,
                                                    const int* __restrict__ batch,
                                                    float* __restrict__ pooled,
                                                    int* __restrict__ gcnt, int N) {
  const int g = blockIdx.x, s = blockIdx.y;  // gridDim.y = 8 splits
  const int t = threadIdx.x;
  __shared__ int range[2];
  __shared__ float sums[256];
  if (t < 2) {
    int target = g + t;
    int lo = 0, hi = N;
    while (lo < hi) {
      int mid = (lo + hi) >> 1;
      if (batch[mid] < target) lo = mid + 1;
      else hi = mid;
    }
    range[t] = lo;
  }
  __syncthreads();
  int beg = range[0], end = range[1];
  if (s == 0 && t == 0) gcnt[g] = end - beg;
  int col = t & 127, half = t >> 7;
  float acc = 0.f;
  for (int n = beg + s * 2 + half; n < end; n += 16) {
    acc += __uint_as_float(((uint)x[(size_t)n * HDIM + col]) << 16);
  }
  sums[t] = acc;
  __syncthreads();
  if (t < 128) atomicAdd(&pooled[g * HDIM + t], sums[t] + sums[t + 128]);
}

__global__ __launch_bounds__(256) void out_final(const float* __restrict__ pooled,
                                                 const int* __restrict__ gcnt,
                                                 const float* __restrict__ W_out,
                                                 const float* __restrict__ b_out,
                                                 float* __restrict__ out, int G, int C) {
  int i = blockIdx.x * 256 + threadIdx.x;
  if (i >= G * C) return;
  int g = i / C, c = i - g * C;
  float inv = 1.f / (float)max(gcnt[g], 1);
  const float* pg = pooled + g * HDIM;
  float o = 0.f;
  for (int h = 0; h < HDIM; ++h) o += pg[h] * W_out[h * C + c];
  out[i] = b_out[c] + o * inv;
}

// ---------------- host ----------------

extern "C" void kernel_launch(void* const* d_in, const int* in_sizes, int n_in,
                              void* d_out, int out_size, void* d_ws, size_t ws_size,
                              hipStream_t stream) {
  (void)n_in;
  (void)ws_size;
  const float* x = (const float*)d_in[0];
  const int* ei = (const int*)d_in[1];
  const int* batch = (const int*)d_in[2];
  const float* Ws = (const float*)d_in[4];
  const float* bs = (const float*)d_in[5];
  const float* W_out = (const float*)d_in[6];
  const float* b_out = (const float*)d_in[7];
  float* out = (float*)d_out;

  const int N = in_sizes[0] / HDIM;
  const int E = in_sizes[1] / 2;
  const int L = in_sizes[5] / HDIM;
  const int C = in_sizes[7];
  const int G = out_size / C;
  const int SB = (N + SBMASK) >> SBITS;      // sub-buckets of 256 nodes
  const int cap = E / SB + 2048;             // per-sub-bucket capacity (~32 sigma)

  char* p = (char*)d_ws;
  auto carve = [&](size_t bytes) {
    char* r = p;
    p += (bytes + 255) & ~(size_t)255;
    return r;
  };
  int* bktcur = (int*)carve(SBMAX * 64);     // one 64B line per counter
  float* dis = (float*)carve((size_t)N * 4);
  int* degs = (int*)carve((size_t)N * 4);
  int* rowptr = (int*)carve((size_t)(N + 1) * 4);
  int* sbtot = (int*)carve(SBMAX * 4);
  int* sbbase = (int*)carve(SBMAX * 4);
  uint* bkt = (uint*)carve((size_t)SB * cap * 4);
  uint* colw = (uint*)carve(((size_t)E + 4 * (size_t)N + 64) * 4);
  ushort* Wsw = (ushort*)carve((size_t)L * HDIM * HDIM * 2);
  ushort* xw = (ushort*)carve((size_t)N * HDIM * 2);
  ushort* y0 = (ushort*)carve((size_t)N * HDIM * 2);
  ushort* y1 = (ushort*)carve((size_t)N * HDIM * 2);
  float* pooled = (float*)carve((size_t)G * HDIM * 4 + (size_t)G * 4);
  int* gcnt = (int*)(pooled + (size_t)G * HDIM);

  hipMemsetAsync(bktcur, 0, SBMAX * 64, stream);
  hipMemsetAsync(pooled, 0, (size_t)G * HDIM * 4 + (size_t)G * 4, stream);

  bucket_edges<<<(E + 2047) / 2048, 256, 0, stream>>>(ei, bktcur, bkt, E, cap);
  csr_count<<<SB, 256, 0, stream>>>(bkt, bktcur, dis, degs, sbtot, cap, N);
  scan_sb<<<1, SBMAX, 0, stream>>>(sbtot, sbbase, rowptr, SB, N);
  csr_place<<<SB, 256, 0, stream>>>(bkt, bktcur, sbbase, dis, degs, rowptr, colw, cap, N);
  swz_w<<<(L * HDIM * HDIM + 255) / 256, 256, 0, stream>>>(Ws, Wsw, L * HDIM * HDIM);

  const int ntiles = (N + 63) / 64;
  const int gb = 768;  // persistent: 3 blocks/CU (49.4 KB LDS)
  gemm_kernel<true><<<gb, 256, 0, stream>>>(x, Wsw, xw, N, ntiles);
  agg_kernel<<<(N + 3) / 4, 256, 0, stream>>>(xw, colw, rowptr, bs, y0, N);
  ushort* xc = y0;
  ushort* xn = y1;
  for (int l = 1; l < L; ++l) {
    gemm_kernel<false><<<gb, 256, 0, stream>>>(xc, Wsw + (size_t)l * HDIM * HDIM, xw, N, ntiles);
    agg_kernel<<<(N + 3) / 4, 256, 0, stream>>>(xw, colw, rowptr, bs + (size_t)l * HDIM, xn, N);
    ushort* tmp = xc;
    xc = xn;
    xn = tmp;
  }
  pool_partial<<<dim3(G, 8), 256, 0, stream>>>(xc, batch, pooled, gcnt, N);
  out_final<<<(G * C + 255) / 256, 256, 0, stream>>>(pooled, gcnt, W_out, b_out, out, G, C);
}